// Round 1
// baseline (56.871 us; speedup 1.0000x reference)
//
#include <hip/hip_runtime.h>

// Problem dims (fixed by reference)
#define BB   256   // batch
#define DIM  512
#define NN   196
#define TB   8     // b-tile in prep kernel
#define TI   64    // i-tile in prep kernel

// ---------------------------------------------------------------------------
// Kernel 1: prep — compute w[b,i] = (mem[b,i] + b_mem[i]) * v1[b,i] + v2[b,i]
//   mem[b,i] = sum_d memory[-1][b,d] * W_mem[d,i]
//   v1[b,i]  = sum_d u[b,d] * W_concat[i,     d]   (u = control[-1]*W_attn)
//   v2[b,i]  = sum_d u[b,d] * W_concat[DIM+i, d]
// grid (BB/TB, DIM/TI) = (32, 8) blocks x 256 threads.
// W_concat rows are accessed transposed -> per-k-tile LDS transpose.
// ---------------------------------------------------------------------------
__global__ __launch_bounds__(256) void prep_kernel(
    const float* __restrict__ memory,    // (2,BB,DIM)
    const float* __restrict__ control,   // (2,BB,DIM)
    const float* __restrict__ W_mem,     // (DIM,DIM) row-major [d][i]
    const float* __restrict__ b_mem,     // (DIM)
    const float* __restrict__ W_concat,  // (2*DIM, DIM) row-major [c][j]
    const float* __restrict__ W_attn,    // (DIM,1)
    float* __restrict__ w_out)           // (BB, DIM)
{
    // padded stride 513 so the 4 distinct per-wave broadcast addresses hit
    // different banks (512 % 32 == 0 would be same-bank)
    __shared__ float M_lds[TB * 513];
    __shared__ float U_lds[TB * 513];
    __shared__ float WT1[64 * 65];   // [d_local][i_local], +1 pad
    __shared__ float WT2[64 * 65];

    const int tid = threadIdx.x;
    const int b0 = blockIdx.x * TB;
    const int i0 = blockIdx.y * TI;

    const float* mem_in = memory  + (size_t)BB * DIM;  // memory[-1]
    const float* ctl_in = control + (size_t)BB * DIM;  // control[-1]

    // Stage per-b vectors (coalesced rows of 512)
    for (int idx = tid; idx < TB * DIM; idx += 256) {
        const int bb = idx >> 9;        // /512
        const int d  = idx & 511;
        M_lds[bb * 513 + d] = mem_in[(size_t)(b0 + bb) * DIM + d];
        U_lds[bb * 513 + d] = ctl_in[(size_t)(b0 + bb) * DIM + d] * W_attn[d];
    }

    const int il   = tid & 63;      // i within tile
    const int slot = tid >> 6;      // 0..3 ; handles b-rows slot and slot+4
    const int i    = i0 + il;

    // transpose-staging coords
    const int r  = tid >> 4;        // 0..15 (row within 16-row stripe)
    const int c4 = (tid & 15) * 4;  // col group (float4)

    float am0 = 0.f, am1 = 0.f;     // mem accumulators
    float a10 = 0.f, a11 = 0.f;     // v1
    float a20 = 0.f, a21 = 0.f;     // v2

    for (int kt = 0; kt < DIM; kt += 64) {
        __syncthreads();  // prev-iter compute done (and first-iter M/U staged)

        // stage 64x64 tiles of W_concat rows [i0..i0+63] / [DIM+i0..], cols [kt..kt+63]
        // load coalesced along d, store transposed to LDS
        #pragma unroll
        for (int rr = 0; rr < 64; rr += 16) {
            const float4 q1 = *(const float4*)&W_concat[(size_t)(i0 + rr + r) * DIM + kt + c4];
            const float4 q2 = *(const float4*)&W_concat[(size_t)(DIM + i0 + rr + r) * DIM + kt + c4];
            WT1[(c4 + 0) * 65 + rr + r] = q1.x;
            WT1[(c4 + 1) * 65 + rr + r] = q1.y;
            WT1[(c4 + 2) * 65 + rr + r] = q1.z;
            WT1[(c4 + 3) * 65 + rr + r] = q1.w;
            WT2[(c4 + 0) * 65 + rr + r] = q2.x;
            WT2[(c4 + 1) * 65 + rr + r] = q2.y;
            WT2[(c4 + 2) * 65 + rr + r] = q2.z;
            WT2[(c4 + 3) * 65 + rr + r] = q2.w;
        }
        __syncthreads();

        #pragma unroll 8
        for (int dd = 0; dd < 64; ++dd) {
            const int d = kt + dd;
            const float wm = W_mem[(size_t)d * DIM + i];  // coalesced over il, L1-broadcast across waves
            const float c1 = WT1[dd * 65 + il];
            const float c2 = WT2[dd * 65 + il];
            const float m0 = M_lds[slot * 513 + d];
            const float u0 = U_lds[slot * 513 + d];
            const float m1 = M_lds[(slot + 4) * 513 + d];
            const float u1 = U_lds[(slot + 4) * 513 + d];
            am0 = fmaf(m0, wm, am0);
            a10 = fmaf(u0, c1, a10);
            a20 = fmaf(u0, c2, a20);
            am1 = fmaf(m1, wm, am1);
            a11 = fmaf(u1, c1, a11);
            a21 = fmaf(u1, c2, a21);
        }
    }

    const float bm = b_mem[i];
    w_out[(size_t)(b0 + slot)     * DIM + i] = (am0 + bm) * a10 + a20;
    w_out[(size_t)(b0 + slot + 4) * DIM + i] = (am1 + bm) * a11 + a21;
}

// ---------------------------------------------------------------------------
// Kernel 2: per-b streaming pass over know.
//   logits[n] = sum_d know[b,d,n] * w[b,d]
//   ksum[n]   = sum_d know[b,d,n]
//   out[b,n]  = softmax_n(logits)[n] * ksum[n]
// grid BB blocks x (256,2) threads. ty splits d-range in halves.
// ---------------------------------------------------------------------------
__global__ __launch_bounds__(512) void read_kernel(
    const float* __restrict__ know,  // (BB, DIM, NN)
    const float* __restrict__ w,     // (BB, DIM)
    float* __restrict__ out)         // (BB, NN)
{
    __shared__ float w_s[DIM];
    __shared__ float lgs[512];
    __shared__ float kss[512];
    __shared__ float red[512];

    const int tx  = threadIdx.x;     // n (0..255, active <196)
    const int ty  = threadIdx.y;     // d-half
    const int tid = ty * 256 + tx;
    const int b   = blockIdx.x;

    w_s[tid] = w[(size_t)b * DIM + tid];
    __syncthreads();

    float lg = 0.f, ks = 0.f;
    if (tx < NN) {
        const float* kp = know + (size_t)b * DIM * NN + (size_t)ty * 256 * NN + tx;
        const float* wp = w_s + ty * 256;
        #pragma unroll 8
        for (int d = 0; d < 256; ++d) {
            const float kv = kp[(size_t)d * NN];
            lg = fmaf(kv, wp[d], lg);
            ks += kv;
        }
    }
    lgs[tid] = lg;
    kss[tid] = ks;
    __syncthreads();
    if (ty == 0) {
        lg = lgs[tx] + lgs[256 + tx];
        ks = kss[tx] + kss[256 + tx];
    }

    // block max over the 196 logits
    red[tid] = (ty == 0 && tx < NN) ? lg : -3.4e38f;
    __syncthreads();
    for (int s = 256; s >= 1; s >>= 1) {
        if (tid < s) red[tid] = fmaxf(red[tid], red[tid + s]);
        __syncthreads();
    }
    const float mx = red[0];
    __syncthreads();

    const float e = (ty == 0 && tx < NN) ? __expf(lg - mx) : 0.f;
    red[tid] = e;
    __syncthreads();
    for (int s = 256; s >= 1; s >>= 1) {
        if (tid < s) red[tid] += red[tid + s];
        __syncthreads();
    }
    const float sm = red[0];

    if (ty == 0 && tx < NN) out[(size_t)b * NN + tx] = e / sm * ks;
}

// ---------------------------------------------------------------------------
extern "C" void kernel_launch(void* const* d_in, const int* in_sizes, int n_in,
                              void* d_out, int out_size, void* d_ws, size_t ws_size,
                              hipStream_t stream) {
    const float* memory   = (const float*)d_in[0];
    const float* know     = (const float*)d_in[1];
    const float* control  = (const float*)d_in[2];
    const float* W_mem    = (const float*)d_in[3];
    const float* b_mem    = (const float*)d_in[4];
    const float* W_concat = (const float*)d_in[5];
    // d_in[6] = b_concat : shifts logits uniformly over n -> softmax-invariant, unused
    const float* W_attn   = (const float*)d_in[7];
    // d_in[8] = b_attn   : same, unused
    float* w_ws = (float*)d_ws;          // (BB, DIM) = 512 KB scratch
    float* outp = (float*)d_out;         // (BB, NN) f32

    dim3 g1(BB / TB, DIM / TI);          // (32, 8)
    prep_kernel<<<g1, dim3(256), 0, stream>>>(memory, control, W_mem, b_mem,
                                              W_concat, W_attn, w_ws);
    read_kernel<<<dim3(BB), dim3(256, 2), 0, stream>>>(know, w_ws, outp);
}